// Round 1
// baseline (3144.325 us; speedup 1.0000x reference)
//
#include <hip/hip_runtime.h>

#define SQ 1024
#define DM 1024
#define NH 16
#define HD 64
#define NL 6
#define DFF 4096
#define EPS 1.1920929e-07f

typedef __attribute__((ext_vector_type(8))) short short8;
typedef __attribute__((ext_vector_type(4))) float floatx4;

__device__ __forceinline__ unsigned short f2b(float f) {
    union { float f; unsigned int u; } x; x.f = f;
    unsigned int r = x.u + 0x7fffu + ((x.u >> 16) & 1u);
    return (unsigned short)(r >> 16);
}

__device__ __forceinline__ float wsum(float v) {
#pragma unroll
    for (int m = 32; m >= 1; m >>= 1) v += __shfl_xor(v, m, 64);
    return v;
}
__device__ __forceinline__ float wmax(float v) {
#pragma unroll
    for (int m = 32; m >= 1; m >>= 1) v = fmaxf(v, __shfl_xor(v, m, 64));
    return v;
}
// block = 256 threads (4 waves)
__device__ __forceinline__ float bsum(float v) {
    __shared__ float sh[4];
    v = wsum(v);
    __syncthreads();
    if ((threadIdx.x & 63) == 0) sh[threadIdx.x >> 6] = v;
    __syncthreads();
    return sh[0] + sh[1] + sh[2] + sh[3];
}
__device__ __forceinline__ float bmax(float v) {
    __shared__ float sh[4];
    v = wmax(v);
    __syncthreads();
    if ((threadIdx.x & 63) == 0) sh[threadIdx.x >> 6] = v;
    __syncthreads();
    return fmaxf(fmaxf(sh[0], sh[1]), fmaxf(sh[2], sh[3]));
}

// ---- f32 -> bf16 weight conversion (grid-stride) ----
__global__ void convert_w(const float* __restrict__ in, unsigned short* __restrict__ out, long n) {
    long i = (long)blockIdx.x * 256 + threadIdx.x;
    long stride = (long)gridDim.x * 256;
    for (; i < n; i += stride) out[i] = f2b(in[i]);
}

// ---- markov mask prep: inclusive scan of (levels==0) -> cpad[1..1024], cpad[0]=0 ----
__global__ void scan_levels(const int* __restrict__ levels, int* __restrict__ cpad) {
    __shared__ int sh[SQ];
    int t = threadIdx.x;
    sh[t] = (levels[t] == 0) ? 1 : 0;
    __syncthreads();
    for (int off = 1; off < SQ; off <<= 1) {
        int v = (t >= off) ? sh[t - off] : 0;
        __syncthreads();
        sh[t] += v;
        __syncthreads();
    }
    cpad[t + 1] = sh[t];
    if (t == 0) cpad[0] = 0;
}

__global__ void build_mask(const int* __restrict__ levels, const int* __restrict__ sidx,
                           const int* __restrict__ cpad, unsigned char* __restrict__ mask) {
    int i = blockIdx.x * 256 + threadIdx.x;
    int q = i >> 10, k = i & 1023;
    bool causal = q >= k;
    bool same = sidx[q] == sidx[k];
    int cnt = cpad[q] - cpad[k + 1];
    bool markov = (levels[k] == 0) && (cnt > 0);
    mask[i] = (causal && same && !markov) ? 1 : 0;
}

// ---- row-wise rms over 1024 cols; optional dual f32 out + bf16 out ----
__global__ void rms_kernel(const float* __restrict__ in, float* o1, float* o2, unsigned short* ob) {
    int row = blockIdx.x, t = threadIdx.x;
    const float* rp = in + (size_t)row * DM;
    float v[4]; float ss = 0.f;
#pragma unroll
    for (int j = 0; j < 4; ++j) { v[j] = rp[t + j * 256]; ss += v[j] * v[j]; }
    ss = bsum(ss);
    float inv = rsqrtf(ss / (float)DM + EPS);
#pragma unroll
    for (int j = 0; j < 4; ++j) {
        float o = v[j] * inv;
        int c = t + j * 256;
        if (o1) o1[(size_t)row * DM + c] = o;
        if (o2) o2[(size_t)row * DM + c] = o;
        if (ob) ob[(size_t)row * DM + c] = f2b(o);
    }
}

// ---- xl = l0*x + l1*x0 (write f32), xn = rms(xl) (write bf16) ----
__global__ void xl_rms(const float* __restrict__ x, const float* __restrict__ x0,
                       const float* __restrict__ lam2, float* __restrict__ xl,
                       unsigned short* __restrict__ xnb) {
    int row = blockIdx.x, t = threadIdx.x;
    float l0 = lam2[0], l1 = lam2[1];
    const float* xp = x + (size_t)row * DM;
    const float* x0p = x0 + (size_t)row * DM;
    float v[4]; float ss = 0.f;
#pragma unroll
    for (int j = 0; j < 4; ++j) {
        int c = t + j * 256;
        v[j] = l0 * xp[c] + l1 * x0p[c];
        ss += v[j] * v[j];
    }
    ss = bsum(ss);
    float inv = rsqrtf(ss / (float)DM + EPS);
#pragma unroll
    for (int j = 0; j < 4; ++j) {
        int c = t + j * 256;
        xl[(size_t)row * DM + c] = v[j];
        xnb[(size_t)row * DM + c] = f2b(v[j] * inv);
    }
}

// ---- per-(s,head) rms over 64 + RoPE, for q and k; f32 in, bf16 out ----
__global__ void qk_norm_rope(const float* __restrict__ qf, const float* __restrict__ kf,
                             unsigned short* __restrict__ qb, unsigned short* __restrict__ kb) {
    int wid = blockIdx.x * 4 + (threadIdx.x >> 6);   // 0..32767
    int lane = threadIdx.x & 63;
    int which = wid >> 14;          // 0 = q, 1 = k
    int idx = wid & 16383;
    int s = idx >> 4;
    int h = idx & 15;
    const float* src = (which ? kf : qf) + (size_t)s * DM + h * HD;
    float v = src[lane];
    float ss = v * v;
#pragma unroll
    for (int m = 32; m >= 1; m >>= 1) ss += __shfl_xor(ss, m, 64);
    v *= rsqrtf(ss / (float)HD + EPS);
    float partner = __shfl_xor(v, 32, 64);
    int j = lane & 31;
    float invf = expf(-((float)(2 * j) / (float)HD) * 9.210340371976184f); // 10000^{-2j/64}
    float fr = (float)s * invf;
    float c = cosf(fr), sn = sinf(fr);
    float o = v * c + ((lane < 32) ? sn : -sn) * partner;
    unsigned short* dst = (which ? kb : qb);
    dst[(size_t)s * DM + h * HD + lane] = f2b(o);
}

// ---- v blend with v1 (captured at layer 0), write transposed bf16 vt[c][s] ----
__global__ void v_blend(const float* __restrict__ v, float* __restrict__ v1,
                        unsigned short* __restrict__ vt, const float* __restrict__ lambp,
                        int first) {
    int i = blockIdx.x * 256 + threadIdx.x;   // 0..S*D-1
    int s = i >> 10, c = i & 1023;
    float val = v[i];
    float l = lambp[0];
    float v1v;
    if (first) { v1[i] = val; v1v = val; } else v1v = v1[i];
    float o = (1.f - l) * val + l * v1v;
    vt[(size_t)c * SQ + s] = f2b(o);
}

// ---- masked softmax over k for one (h,q) row; f32 scores in, bf16 P out ----
__global__ void softmax_kernel(const float* __restrict__ scores, const unsigned char* __restrict__ mask,
                               unsigned short* __restrict__ p) {
    int q = blockIdx.x, h = blockIdx.y, t = threadIdx.x;
    const float* sp = scores + ((size_t)h * SQ + q) * SQ;
    const unsigned char* mp = mask + (size_t)q * SQ;
    unsigned short* pp = p + ((size_t)h * SQ + q) * SQ;
    float vals[4]; float mx = -3.0e38f;
#pragma unroll
    for (int j = 0; j < 4; ++j) {
        int k = t + j * 256;
        float s = mp[k] ? sp[k] : -1e30f;
        vals[j] = s;
        mx = fmaxf(mx, s);
    }
    mx = bmax(mx);
    float sum = 0.f;
#pragma unroll
    for (int j = 0; j < 4; ++j) { vals[j] = __expf(vals[j] - mx); sum += vals[j]; }
    sum = bsum(sum);
    float inv = 1.f / sum;
#pragma unroll
    for (int j = 0; j < 4; ++j) pp[t + j * 256] = f2b(vals[j] * inv);
}

// ---- direct-load MFMA GEMM: C[z] = act(scale * A[z] * B[z]^T + add) ----
// one wave (64 thr) per 16x16 output tile. A: (M,K) row-major lda, B: (N,K) row-major ldb.
// frag layouts (gfx950 16x16x32 bf16, HW-verified): A[m=lane&15][k=(lane>>4)*8+j],
// C/D: col=lane&15, row=(lane>>4)*4+reg.
__global__ void gemm(const unsigned short* __restrict__ A, int lda, long long sA,
                     const unsigned short* __restrict__ B, int ldb, long long sB,
                     float* Cf, unsigned short* Cb, int ldc, long long sC,
                     const float* addsrc, int ldadd,
                     int K, float scale, int act) {
    int lane = threadIdx.x;
    int n0 = blockIdx.x * 16, m0 = blockIdx.y * 16, z = blockIdx.z;
    int r = lane & 15, q4 = lane >> 4;
    const unsigned short* Ap = A + (size_t)z * sA + (size_t)(m0 + r) * lda + q4 * 8;
    const unsigned short* Bp = B + (size_t)z * sB + (size_t)(n0 + r) * ldb + q4 * 8;
    floatx4 acc = {0.f, 0.f, 0.f, 0.f};
    for (int k = 0; k < K; k += 32) {
        short8 a = *(const short8*)(Ap + k);
        short8 b = *(const short8*)(Bp + k);
        acc = __builtin_amdgcn_mfma_f32_16x16x32_bf16(a, b, acc, 0, 0, 0);
    }
    int col = n0 + r;
    size_t cz = (size_t)z * sC;
#pragma unroll
    for (int j = 0; j < 4; ++j) {
        int row = m0 + q4 * 4 + j;
        float v = acc[j] * scale;
        if (addsrc) v += addsrc[(size_t)row * ldadd + col];
        if (act == 1) { v = fmaxf(v, 0.f); v = v * v; }
        if (Cf) Cf[cz + (size_t)row * ldc + col] = v;
        if (Cb) Cb[cz + (size_t)row * ldc + col] = f2b(v);
    }
}

extern "C" void kernel_launch(void* const* d_in, const int* in_sizes, int n_in,
                              void* d_out, int out_size, void* d_ws, size_t ws_size,
                              hipStream_t stream) {
    const float* x_in    = (const float*)d_in[0];
    const float* Wq      = (const float*)d_in[1];
    const float* Wk      = (const float*)d_in[2];
    const float* Wv      = (const float*)d_in[3];
    const float* Wo      = (const float*)d_in[4];
    const float* lamb    = (const float*)d_in[5];
    const float* lambdas = (const float*)d_in[6];
    const float* Wfc     = (const float*)d_in[7];
    const float* Wp      = (const float*)d_in[8];
    const int*   levels  = (const int*)d_in[9];
    const int*   sidx    = (const int*)d_in[10];
    float* out = (float*)d_out;

    char* ws = (char*)d_ws;
    size_t off = 0;
    auto alloc = [&](size_t b) { void* p = ws + off; off = (off + b + 255) & ~(size_t)255; return p; };

    unsigned short* wq_b  = (unsigned short*)alloc((size_t)NL * DM * DM * 2);
    unsigned short* wk_b  = (unsigned short*)alloc((size_t)NL * DM * DM * 2);
    unsigned short* wv_b  = (unsigned short*)alloc((size_t)NL * DM * DM * 2);
    unsigned short* wo_b  = (unsigned short*)alloc((size_t)NL * DM * DM * 2);
    unsigned short* wfc_b = (unsigned short*)alloc((size_t)NL * DFF * DM * 2);
    unsigned short* wp_b  = (unsigned short*)alloc((size_t)NL * DM * DFF * 2);
    int* cpad             = (int*)alloc((SQ + 1) * 4);
    unsigned char* mask   = (unsigned char*)alloc((size_t)SQ * SQ);
    float* x    = (float*)alloc((size_t)SQ * DM * 4);
    float* x0   = (float*)alloc((size_t)SQ * DM * 4);
    float* xl   = (float*)alloc((size_t)SQ * DM * 4);
    float* qf   = (float*)alloc((size_t)SQ * DM * 4);
    float* kf   = (float*)alloc((size_t)SQ * DM * 4);
    float* vf   = (float*)alloc((size_t)SQ * DM * 4);
    float* v1   = (float*)alloc((size_t)SQ * DM * 4);
    unsigned short* xn_b = (unsigned short*)alloc((size_t)SQ * DM * 2);
    unsigned short* qb   = (unsigned short*)alloc((size_t)SQ * DM * 2);
    unsigned short* kb   = (unsigned short*)alloc((size_t)SQ * DM * 2);
    unsigned short* vt   = (unsigned short*)alloc((size_t)SQ * DM * 2);
    unsigned short* y_b  = (unsigned short*)alloc((size_t)SQ * DM * 2);
    unsigned short* xh_b = (unsigned short*)alloc((size_t)SQ * DM * 2);
    float* scores        = (float*)alloc((size_t)NH * SQ * SQ * 4);
    unsigned short* p_b  = (unsigned short*)alloc((size_t)NH * SQ * SQ * 2);
    unsigned short* h_b  = (unsigned short*)alloc((size_t)SQ * DFF * 2);

    if (off > ws_size) return;  // workspace too small — fail cleanly

    // weights -> bf16
    convert_w<<<4096, 256, 0, stream>>>(Wq, wq_b, (long)NL * DM * DM);
    convert_w<<<4096, 256, 0, stream>>>(Wk, wk_b, (long)NL * DM * DM);
    convert_w<<<4096, 256, 0, stream>>>(Wv, wv_b, (long)NL * DM * DM);
    convert_w<<<4096, 256, 0, stream>>>(Wo, wo_b, (long)NL * DM * DM);
    convert_w<<<8192, 256, 0, stream>>>(Wfc, wfc_b, (long)NL * DFF * DM);
    convert_w<<<8192, 256, 0, stream>>>(Wp, wp_b, (long)NL * DM * DFF);

    scan_levels<<<1, 1024, 0, stream>>>(levels, cpad);
    build_mask<<<4096, 256, 0, stream>>>(levels, sidx, cpad, mask);

    // x = rms(x_in); x0 = x
    rms_kernel<<<SQ, 256, 0, stream>>>(x_in, x, x0, nullptr);

    for (int i = 0; i < NL; ++i) {
        xl_rms<<<SQ, 256, 0, stream>>>(x, x0, lambdas + 2 * i, xl, xn_b);

        // q,k,v projections
        gemm<<<dim3(64, 64, 1), 64, 0, stream>>>(xn_b, DM, 0, wq_b + (size_t)i * DM * DM, DM, 0,
                                                 qf, nullptr, DM, 0, nullptr, 0, DM, 1.f, 0);
        gemm<<<dim3(64, 64, 1), 64, 0, stream>>>(xn_b, DM, 0, wk_b + (size_t)i * DM * DM, DM, 0,
                                                 kf, nullptr, DM, 0, nullptr, 0, DM, 1.f, 0);
        gemm<<<dim3(64, 64, 1), 64, 0, stream>>>(xn_b, DM, 0, wv_b + (size_t)i * DM * DM, DM, 0,
                                                 vf, nullptr, DM, 0, nullptr, 0, DM, 1.f, 0);

        qk_norm_rope<<<8192, 256, 0, stream>>>(qf, kf, qb, kb);
        v_blend<<<4096, 256, 0, stream>>>(vf, v1, vt, lamb + i, (i == 0) ? 1 : 0);

        // scores[h] = scale * q_h k_h^T
        gemm<<<dim3(64, 64, NH), 64, 0, stream>>>(qb, DM, HD, kb, DM, HD,
                                                  scores, nullptr, SQ, (long long)SQ * SQ,
                                                  nullptr, 0, HD, 0.125f, 0);
        softmax_kernel<<<dim3(SQ, NH), 256, 0, stream>>>(scores, mask, p_b);

        // y[s, h*64+d] = P_h v_h
        gemm<<<dim3(4, 64, NH), 64, 0, stream>>>(p_b, SQ, (long long)SQ * SQ, vt, SQ, (long long)HD * SQ,
                                                 nullptr, y_b, DM, HD, nullptr, 0, SQ, 1.f, 0);

        // x = xl + y @ Wo^T
        gemm<<<dim3(64, 64, 1), 64, 0, stream>>>(y_b, DM, 0, wo_b + (size_t)i * DM * DM, DM, 0,
                                                 x, nullptr, DM, 0, xl, DM, DM, 1.f, 0);

        // FFN
        rms_kernel<<<SQ, 256, 0, stream>>>(x, nullptr, nullptr, xh_b);
        gemm<<<dim3(256, 64, 1), 64, 0, stream>>>(xh_b, DM, 0, wfc_b + (size_t)i * DFF * DM, DM, 0,
                                                  nullptr, h_b, DFF, 0, nullptr, 0, DM, 1.f, 1);
        gemm<<<dim3(64, 64, 1), 64, 0, stream>>>(h_b, DFF, 0, wp_b + (size_t)i * DM * DFF, DFF, 0,
                                                 x, nullptr, DM, 0, x, DM, DFF, 1.f, 0);
    }

    rms_kernel<<<SQ, 256, 0, stream>>>(x, out, nullptr, nullptr);
}

// Round 2
// 1655.332 us; speedup vs baseline: 1.8995x; 1.8995x over previous
//
#include <hip/hip_runtime.h>

#define SQ 1024
#define DM 1024
#define NH 16
#define HD 64
#define NL 6
#define DFF 4096
#define EPS 1.1920929e-07f

typedef __attribute__((ext_vector_type(8))) short short8;
typedef __attribute__((ext_vector_type(4))) float floatx4;
typedef __attribute__((address_space(1))) const unsigned int GU32;
typedef __attribute__((address_space(3))) unsigned int LU32;

__device__ __forceinline__ unsigned short f2b(float f) {
    union { float f; unsigned int u; } x; x.f = f;
    unsigned int r = x.u + 0x7fffu + ((x.u >> 16) & 1u);
    return (unsigned short)(r >> 16);
}

__device__ __forceinline__ float wsum(float v) {
#pragma unroll
    for (int m = 32; m >= 1; m >>= 1) v += __shfl_xor(v, m, 64);
    return v;
}
__device__ __forceinline__ float wmax(float v) {
#pragma unroll
    for (int m = 32; m >= 1; m >>= 1) v = fmaxf(v, __shfl_xor(v, m, 64));
    return v;
}
__device__ __forceinline__ float bsum(float v) {
    __shared__ float sh[4];
    v = wsum(v);
    __syncthreads();
    if ((threadIdx.x & 63) == 0) sh[threadIdx.x >> 6] = v;
    __syncthreads();
    return sh[0] + sh[1] + sh[2] + sh[3];
}
__device__ __forceinline__ float bmax(float v) {
    __shared__ float sh[4];
    v = wmax(v);
    __syncthreads();
    if ((threadIdx.x & 63) == 0) sh[threadIdx.x >> 6] = v;
    __syncthreads();
    return fmaxf(fmaxf(sh[0], sh[1]), fmaxf(sh[2], sh[3]));
}

// ---- f32 -> bf16 weight conversion, float4 vectorized ----
__global__ void convert_w(const float* __restrict__ in, unsigned short* __restrict__ out, long n4) {
    long i = (long)blockIdx.x * 256 + threadIdx.x;
    long stride = (long)gridDim.x * 256;
    for (; i < n4; i += stride) {
        float4 v = ((const float4*)in)[i];
        ushort4 o;
        o.x = f2b(v.x); o.y = f2b(v.y); o.z = f2b(v.z); o.w = f2b(v.w);
        ((ushort4*)out)[i] = o;
    }
}

// ---- markov mask prep ----
__global__ void scan_levels(const int* __restrict__ levels, int* __restrict__ cpad) {
    __shared__ int sh[SQ];
    int t = threadIdx.x;
    sh[t] = (levels[t] == 0) ? 1 : 0;
    __syncthreads();
    for (int off = 1; off < SQ; off <<= 1) {
        int v = (t >= off) ? sh[t - off] : 0;
        __syncthreads();
        sh[t] += v;
        __syncthreads();
    }
    cpad[t + 1] = sh[t];
    if (t == 0) cpad[0] = 0;
}

__global__ void build_mask(const int* __restrict__ levels, const int* __restrict__ sidx,
                           const int* __restrict__ cpad, unsigned char* __restrict__ mask) {
    int i = blockIdx.x * 256 + threadIdx.x;
    int q = i >> 10, k = i & 1023;
    bool causal = q >= k;
    bool same = sidx[q] == sidx[k];
    int cnt = cpad[q] - cpad[k + 1];
    bool markov = (levels[k] == 0) && (cnt > 0);
    mask[i] = (causal && same && !markov) ? 1 : 0;
}

// ---- row-wise rms ----
__global__ void rms_kernel(const float* __restrict__ in, float* o1, float* o2, unsigned short* ob) {
    int row = blockIdx.x, t = threadIdx.x;
    const float* rp = in + (size_t)row * DM;
    float v[4]; float ss = 0.f;
#pragma unroll
    for (int j = 0; j < 4; ++j) { v[j] = rp[t + j * 256]; ss += v[j] * v[j]; }
    ss = bsum(ss);
    float inv = rsqrtf(ss / (float)DM + EPS);
#pragma unroll
    for (int j = 0; j < 4; ++j) {
        float o = v[j] * inv;
        int c = t + j * 256;
        if (o1) o1[(size_t)row * DM + c] = o;
        if (o2) o2[(size_t)row * DM + c] = o;
        if (ob) ob[(size_t)row * DM + c] = f2b(o);
    }
}

// ---- xl = l0*x + l1*x0 (f32), xn = rms(xl) (bf16) ----
__global__ void xl_rms(const float* __restrict__ x, const float* __restrict__ x0,
                       const float* __restrict__ lam2, float* __restrict__ xl,
                       unsigned short* __restrict__ xnb) {
    int row = blockIdx.x, t = threadIdx.x;
    float l0 = lam2[0], l1 = lam2[1];
    const float* xp = x + (size_t)row * DM;
    const float* x0p = x0 + (size_t)row * DM;
    float v[4]; float ss = 0.f;
#pragma unroll
    for (int j = 0; j < 4; ++j) {
        int c = t + j * 256;
        v[j] = l0 * xp[c] + l1 * x0p[c];
        ss += v[j] * v[j];
    }
    ss = bsum(ss);
    float inv = rsqrtf(ss / (float)DM + EPS);
#pragma unroll
    for (int j = 0; j < 4; ++j) {
        int c = t + j * 256;
        xl[(size_t)row * DM + c] = v[j];
        xnb[(size_t)row * DM + c] = f2b(v[j] * inv);
    }
}

// ---- per-(s,head) rms + RoPE for q and k ----
__global__ void qk_norm_rope(const float* __restrict__ qf, const float* __restrict__ kf,
                             unsigned short* __restrict__ qb, unsigned short* __restrict__ kb) {
    int wid = blockIdx.x * 4 + (threadIdx.x >> 6);
    int lane = threadIdx.x & 63;
    int which = wid >> 14;
    int idx = wid & 16383;
    int s = idx >> 4;
    int h = idx & 15;
    const float* src = (which ? kf : qf) + (size_t)s * DM + h * HD;
    float v = src[lane];
    float ss = v * v;
#pragma unroll
    for (int m = 32; m >= 1; m >>= 1) ss += __shfl_xor(ss, m, 64);
    v *= rsqrtf(ss / (float)HD + EPS);
    float partner = __shfl_xor(v, 32, 64);
    int j = lane & 31;
    float invf = expf(-((float)(2 * j) / (float)HD) * 9.210340371976184f);
    float fr = (float)s * invf;
    float c = cosf(fr), sn = sinf(fr);
    float o = v * c + ((lane < 32) ? sn : -sn) * partner;
    unsigned short* dst = (which ? kb : qb);
    dst[(size_t)s * DM + h * HD + lane] = f2b(o);
}

// ---- v blend; write transposed bf16 vt[c][s] ----
__global__ void v_blend(const float* __restrict__ v, float* __restrict__ v1,
                        unsigned short* __restrict__ vt, const float* __restrict__ lambp,
                        int first) {
    int i = blockIdx.x * 256 + threadIdx.x;
    int s = i >> 10, c = i & 1023;
    float val = v[i];
    float l = lambp[0];
    float v1v;
    if (first) { v1[i] = val; v1v = val; } else v1v = v1[i];
    float o = (1.f - l) * val + l * v1v;
    vt[(size_t)c * SQ + s] = f2b(o);
}

// ---- masked softmax ----
__global__ void softmax_kernel(const float* __restrict__ scores, const unsigned char* __restrict__ mask,
                               unsigned short* __restrict__ p) {
    int q = blockIdx.x, h = blockIdx.y, t = threadIdx.x;
    const float* sp = scores + ((size_t)h * SQ + q) * SQ;
    const unsigned char* mp = mask + (size_t)q * SQ;
    unsigned short* pp = p + ((size_t)h * SQ + q) * SQ;
    float vals[4]; float mx = -3.0e38f;
#pragma unroll
    for (int j = 0; j < 4; ++j) {
        int k = t + j * 256;
        float s = mp[k] ? sp[k] : -1e30f;
        vals[j] = s;
        mx = fmaxf(mx, s);
    }
    mx = bmax(mx);
    float sum = 0.f;
#pragma unroll
    for (int j = 0; j < 4; ++j) { vals[j] = __expf(vals[j] - mx); sum += vals[j]; }
    sum = bsum(sum);
    float inv = 1.f / sum;
#pragma unroll
    for (int j = 0; j < 4; ++j) pp[t + j * 256] = f2b(vals[j] * inv);
}

// ---- LDS-tiled MFMA GEMM (m97 structure): C[z] = act(scale*A[z]*B[z]^T + add) ----
// A: (M,K) row-major; B: (N,K) row-major. 256 thr = 4 waves in 2x2; BK=32.
// Staging via global_load_lds width=16 (wave-uniform LDS base + lane*16B).
template<int BM, int BN>
__global__ __launch_bounds__(256, 2)
void gemm_t(const unsigned short* __restrict__ A, int lda, long long sA,
            const unsigned short* __restrict__ B, int ldb, long long sB,
            float* Cf, unsigned short* Cb, int ldc, long long sC,
            const float* __restrict__ addsrc, int ldadd,
            int K, float scale, int act) {
    constexpr int BK = 32;
    constexpr int MI = BM / 32, NI = BN / 32;      // frags per wave (2x2 wave grid)
    constexpr int CA = BM / 16, CB = BN / 16;      // 1KiB staging chunks
    constexpr int CAW = CA / 4, CBW = CB / 4;      // chunks per wave
    __shared__ unsigned short As[BM * BK];
    __shared__ unsigned short Bs[BN * BK];

    int t = threadIdx.x;
    int wave = t >> 6, lane = t & 63;
    int m0 = blockIdx.y * BM, n0 = blockIdx.x * BN;
    int z = blockIdx.z;
    const unsigned short* Ab = A + (size_t)z * sA;
    const unsigned short* Bb = B + (size_t)z * sB;

    int r = lane & 15, q4 = lane >> 4;
    int sr = lane >> 2, sseg = lane & 3;           // staging: row-in-chunk, 16B segment
    int wmo = (wave >> 1) * (BM / 2);
    int wno = (wave & 1) * (BN / 2);

    floatx4 acc[MI][NI] = {};

    for (int k0 = 0; k0 < K; k0 += BK) {
#pragma unroll
        for (int j = 0; j < CAW; ++j) {
            int c = wave * CAW + j;
            const unsigned short* g = Ab + (size_t)(m0 + c * 16 + sr) * lda + k0 + sseg * 8;
            __builtin_amdgcn_global_load_lds((GU32*)g, (LU32*)(As + c * 512), 16, 0, 0);
        }
#pragma unroll
        for (int j = 0; j < CBW; ++j) {
            int c = wave * CBW + j;
            const unsigned short* g = Bb + (size_t)(n0 + c * 16 + sr) * ldb + k0 + sseg * 8;
            __builtin_amdgcn_global_load_lds((GU32*)g, (LU32*)(Bs + c * 512), 16, 0, 0);
        }
        __syncthreads();   // compiler drains vmcnt(0) before s_barrier

        short8 af[MI], bfr[NI];
#pragma unroll
        for (int mi = 0; mi < MI; ++mi)
            af[mi] = *(const short8*)(As + (wmo + mi * 16 + r) * BK + q4 * 8);
#pragma unroll
        for (int ni = 0; ni < NI; ++ni)
            bfr[ni] = *(const short8*)(Bs + (wno + ni * 16 + r) * BK + q4 * 8);
#pragma unroll
        for (int mi = 0; mi < MI; ++mi)
#pragma unroll
            for (int ni = 0; ni < NI; ++ni)
                acc[mi][ni] = __builtin_amdgcn_mfma_f32_16x16x32_bf16(af[mi], bfr[ni], acc[mi][ni], 0, 0, 0);
        __syncthreads();
    }

    size_t cz = (size_t)z * sC;
#pragma unroll
    for (int mi = 0; mi < MI; ++mi) {
#pragma unroll
        for (int ni = 0; ni < NI; ++ni) {
            int col = n0 + wno + ni * 16 + r;
#pragma unroll
            for (int j = 0; j < 4; ++j) {
                int row = m0 + wmo + mi * 16 + q4 * 4 + j;
                float v = acc[mi][ni][j] * scale;
                if (addsrc) v += addsrc[(size_t)row * ldadd + col];
                if (act == 1) { v = fmaxf(v, 0.f); v = v * v; }
                if (Cf) Cf[cz + (size_t)row * ldc + col] = v;
                if (Cb) Cb[cz + (size_t)row * ldc + col] = f2b(v);
            }
        }
    }
}

extern "C" void kernel_launch(void* const* d_in, const int* in_sizes, int n_in,
                              void* d_out, int out_size, void* d_ws, size_t ws_size,
                              hipStream_t stream) {
    const float* x_in    = (const float*)d_in[0];
    const float* Wq      = (const float*)d_in[1];
    const float* Wk      = (const float*)d_in[2];
    const float* Wv      = (const float*)d_in[3];
    const float* Wo      = (const float*)d_in[4];
    const float* lamb    = (const float*)d_in[5];
    const float* lambdas = (const float*)d_in[6];
    const float* Wfc     = (const float*)d_in[7];
    const float* Wp      = (const float*)d_in[8];
    const int*   levels  = (const int*)d_in[9];
    const int*   sidx    = (const int*)d_in[10];
    float* out = (float*)d_out;

    char* ws = (char*)d_ws;
    size_t off = 0;
    auto alloc = [&](size_t b) { void* p = ws + off; off = (off + b + 255) & ~(size_t)255; return p; };

    // NOTE: wq_b/wk_b/wv_b must stay contiguous (z-stride NL*DM*DM for fused QKV),
    // and qf/kf/vf contiguous (z-stride SQ*DM).
    unsigned short* wq_b  = (unsigned short*)alloc((size_t)NL * DM * DM * 2);
    unsigned short* wk_b  = (unsigned short*)alloc((size_t)NL * DM * DM * 2);
    unsigned short* wv_b  = (unsigned short*)alloc((size_t)NL * DM * DM * 2);
    unsigned short* wo_b  = (unsigned short*)alloc((size_t)NL * DM * DM * 2);
    unsigned short* wfc_b = (unsigned short*)alloc((size_t)NL * DFF * DM * 2);
    unsigned short* wp_b  = (unsigned short*)alloc((size_t)NL * DM * DFF * 2);
    int* cpad             = (int*)alloc((SQ + 1) * 4);
    unsigned char* mask   = (unsigned char*)alloc((size_t)SQ * SQ);
    float* x    = (float*)alloc((size_t)SQ * DM * 4);
    float* x0   = (float*)alloc((size_t)SQ * DM * 4);
    float* xl   = (float*)alloc((size_t)SQ * DM * 4);
    float* qf   = (float*)alloc((size_t)SQ * DM * 4);
    float* kf   = (float*)alloc((size_t)SQ * DM * 4);
    float* vf   = (float*)alloc((size_t)SQ * DM * 4);
    float* v1   = (float*)alloc((size_t)SQ * DM * 4);
    unsigned short* xn_b = (unsigned short*)alloc((size_t)SQ * DM * 2);
    unsigned short* qb   = (unsigned short*)alloc((size_t)SQ * DM * 2);
    unsigned short* kb   = (unsigned short*)alloc((size_t)SQ * DM * 2);
    unsigned short* vt   = (unsigned short*)alloc((size_t)SQ * DM * 2);
    unsigned short* y_b  = (unsigned short*)alloc((size_t)SQ * DM * 2);
    unsigned short* xh_b = (unsigned short*)alloc((size_t)SQ * DM * 2);
    float* scores        = (float*)alloc((size_t)NH * SQ * SQ * 4);
    unsigned short* p_b  = (unsigned short*)alloc((size_t)NH * SQ * SQ * 2);
    unsigned short* h_b  = (unsigned short*)alloc((size_t)SQ * DFF * 2);

    if (off > ws_size) return;

    const long long WSTRIDE = (long long)NL * DM * DM;   // wq_b -> wk_b -> wv_b spacing
    const long long XSTRIDE = (long long)SQ * DM;        // qf -> kf -> vf spacing

    convert_w<<<1024, 256, 0, stream>>>(Wq, wq_b, (long)NL * DM * DM / 4);
    convert_w<<<1024, 256, 0, stream>>>(Wk, wk_b, (long)NL * DM * DM / 4);
    convert_w<<<1024, 256, 0, stream>>>(Wv, wv_b, (long)NL * DM * DM / 4);
    convert_w<<<1024, 256, 0, stream>>>(Wo, wo_b, (long)NL * DM * DM / 4);
    convert_w<<<2048, 256, 0, stream>>>(Wfc, wfc_b, (long)NL * DFF * DM / 4);
    convert_w<<<2048, 256, 0, stream>>>(Wp, wp_b, (long)NL * DM * DFF / 4);

    scan_levels<<<1, 1024, 0, stream>>>(levels, cpad);
    build_mask<<<4096, 256, 0, stream>>>(levels, sidx, cpad, mask);

    rms_kernel<<<SQ, 256, 0, stream>>>(x_in, x, x0, nullptr);

    for (int i = 0; i < NL; ++i) {
        xl_rms<<<SQ, 256, 0, stream>>>(x, x0, lambdas + 2 * i, xl, xn_b);

        // fused QKV: z in {0,1,2} selects Wq/Wk/Wv and qf/kf/vf
        gemm_t<128, 128><<<dim3(8, 8, 3), 256, 0, stream>>>(
            xn_b, DM, 0, wq_b + (size_t)i * DM * DM, DM, WSTRIDE,
            qf, nullptr, DM, XSTRIDE, nullptr, 0, DM, 1.f, 0);

        qk_norm_rope<<<8192, 256, 0, stream>>>(qf, kf, qb, kb);
        v_blend<<<4096, 256, 0, stream>>>(vf, v1, vt, lamb + i, (i == 0) ? 1 : 0);

        // scores[h] = 0.125 * q_h k_h^T
        gemm_t<128, 64><<<dim3(16, 8, NH), 256, 0, stream>>>(
            qb, DM, HD, kb, DM, HD,
            scores, nullptr, SQ, (long long)SQ * SQ, nullptr, 0, HD, 0.125f, 0);
        softmax_kernel<<<dim3(SQ, NH), 256, 0, stream>>>(scores, mask, p_b);

        // y = P_h v_h
        gemm_t<64, 64><<<dim3(1, 16, NH), 256, 0, stream>>>(
            p_b, SQ, (long long)SQ * SQ, vt, SQ, (long long)HD * SQ,
            nullptr, y_b, DM, HD, nullptr, 0, SQ, 1.f, 0);

        // x = xl + y @ Wo^T
        gemm_t<64, 64><<<dim3(16, 16, 1), 256, 0, stream>>>(
            y_b, DM, 0, wo_b + (size_t)i * DM * DM, DM, 0,
            x, nullptr, DM, 0, xl, DM, DM, 1.f, 0);

        // FFN
        rms_kernel<<<SQ, 256, 0, stream>>>(x, nullptr, nullptr, xh_b);
        gemm_t<128, 128><<<dim3(32, 8, 1), 256, 0, stream>>>(
            xh_b, DM, 0, wfc_b + (size_t)i * DFF * DM, DM, 0,
            nullptr, h_b, DFF, 0, nullptr, 0, DM, 1.f, 1);
        gemm_t<64, 64><<<dim3(16, 16, 1), 256, 0, stream>>>(
            h_b, DFF, 0, wp_b + (size_t)i * DM * DFF, DFF, 0,
            x, nullptr, DM, 0, x, DM, DFF, 1.f, 0);
    }

    rms_kernel<<<SQ, 256, 0, stream>>>(x, out, nullptr, nullptr);
}

// Round 3
// 1273.759 us; speedup vs baseline: 2.4685x; 1.2996x over previous
//
#include <hip/hip_runtime.h>

#define SQ 1024
#define DM 1024
#define NH 16
#define HD 64
#define NL 6
#define DFF 4096
#define EPS 1.1920929e-07f

typedef __attribute__((ext_vector_type(8))) short short8;
typedef __attribute__((ext_vector_type(4))) float floatx4;
typedef __attribute__((address_space(1))) const unsigned int GU32;
typedef __attribute__((address_space(3))) unsigned int LU32;

__device__ __forceinline__ unsigned short f2b(float f) {
    union { float f; unsigned int u; } x; x.f = f;
    unsigned int r = x.u + 0x7fffu + ((x.u >> 16) & 1u);
    return (unsigned short)(r >> 16);
}

__device__ __forceinline__ float wsum(float v) {
#pragma unroll
    for (int m = 32; m >= 1; m >>= 1) v += __shfl_xor(v, m, 64);
    return v;
}
__device__ __forceinline__ float bsum(float v) {
    __shared__ float sh[4];
    v = wsum(v);
    __syncthreads();
    if ((threadIdx.x & 63) == 0) sh[threadIdx.x >> 6] = v;
    __syncthreads();
    return sh[0] + sh[1] + sh[2] + sh[3];
}

// ---- f32 -> bf16 weight conversion, float4 vectorized ----
__global__ void convert_w(const float* __restrict__ in, unsigned short* __restrict__ out, long n4) {
    long i = (long)blockIdx.x * 256 + threadIdx.x;
    long stride = (long)gridDim.x * 256;
    for (; i < n4; i += stride) {
        float4 v = ((const float4*)in)[i];
        ushort4 o;
        o.x = f2b(v.x); o.y = f2b(v.y); o.z = f2b(v.z); o.w = f2b(v.w);
        ((ushort4*)out)[i] = o;
    }
}

// ---- markov mask prep ----
__global__ void scan_levels(const int* __restrict__ levels, int* __restrict__ cpad) {
    __shared__ int sh[SQ];
    int t = threadIdx.x;
    sh[t] = (levels[t] == 0) ? 1 : 0;
    __syncthreads();
    for (int off = 1; off < SQ; off <<= 1) {
        int v = (t >= off) ? sh[t - off] : 0;
        __syncthreads();
        sh[t] += v;
        __syncthreads();
    }
    cpad[t + 1] = sh[t];
    if (t == 0) cpad[0] = 0;
}

// packed mask: mb[q*16 + w] bit b = allow attention q -> k=(w*64+b)
__global__ void build_mask_bits(const int* __restrict__ levels, const int* __restrict__ sidx,
                                const int* __restrict__ cpad, unsigned long long* __restrict__ mb) {
    int i = blockIdx.x * 256 + threadIdx.x;
    int q = i >> 10, k = i & 1023;
    bool causal = q >= k;
    bool same = sidx[q] == sidx[k];
    int cnt = cpad[q] - cpad[k + 1];
    bool markov = (levels[k] == 0) && (cnt > 0);
    bool pred = causal && same && !markov;
    unsigned long long bal = __ballot(pred);
    if ((threadIdx.x & 63) == 0) mb[(size_t)q * 16 + (k >> 6)] = bal;
}

// ---- row-wise rms ----
__global__ void rms_kernel(const float* __restrict__ in, float* o1, float* o2, unsigned short* ob) {
    int row = blockIdx.x, t = threadIdx.x;
    const float* rp = in + (size_t)row * DM;
    float v[4]; float ss = 0.f;
#pragma unroll
    for (int j = 0; j < 4; ++j) { v[j] = rp[t + j * 256]; ss += v[j] * v[j]; }
    ss = bsum(ss);
    float inv = rsqrtf(ss / (float)DM + EPS);
#pragma unroll
    for (int j = 0; j < 4; ++j) {
        float o = v[j] * inv;
        int c = t + j * 256;
        if (o1) o1[(size_t)row * DM + c] = o;
        if (o2) o2[(size_t)row * DM + c] = o;
        if (ob) ob[(size_t)row * DM + c] = f2b(o);
    }
}

// ---- xl = l0*x + l1*x0 (f32), xn = rms(xl) (bf16) ----
__global__ void xl_rms(const float* __restrict__ x, const float* __restrict__ x0,
                       const float* __restrict__ lam2, float* __restrict__ xl,
                       unsigned short* __restrict__ xnb) {
    int row = blockIdx.x, t = threadIdx.x;
    float l0 = lam2[0], l1 = lam2[1];
    const float* xp = x + (size_t)row * DM;
    const float* x0p = x0 + (size_t)row * DM;
    float v[4]; float ss = 0.f;
#pragma unroll
    for (int j = 0; j < 4; ++j) {
        int c = t + j * 256;
        v[j] = l0 * xp[c] + l1 * x0p[c];
        ss += v[j] * v[j];
    }
    ss = bsum(ss);
    float inv = rsqrtf(ss / (float)DM + EPS);
#pragma unroll
    for (int j = 0; j < 4; ++j) {
        int c = t + j * 256;
        xl[(size_t)row * DM + c] = v[j];
        xnb[(size_t)row * DM + c] = f2b(v[j] * inv);
    }
}

// ---- per-(s,head) rms + RoPE for q and k ----
__global__ void qk_norm_rope(const float* __restrict__ qf, const float* __restrict__ kf,
                             unsigned short* __restrict__ qb, unsigned short* __restrict__ kb) {
    int wid = blockIdx.x * 4 + (threadIdx.x >> 6);
    int lane = threadIdx.x & 63;
    int which = wid >> 14;
    int idx = wid & 16383;
    int s = idx >> 4;
    int h = idx & 15;
    const float* src = (which ? kf : qf) + (size_t)s * DM + h * HD;
    float v = src[lane];
    float ss = v * v;
#pragma unroll
    for (int m = 32; m >= 1; m >>= 1) ss += __shfl_xor(ss, m, 64);
    v *= rsqrtf(ss / (float)HD + EPS);
    float partner = __shfl_xor(v, 32, 64);
    int j = lane & 31;
    float invf = expf(-((float)(2 * j) / (float)HD) * 9.210340371976184f);
    float fr = (float)s * invf;
    float c = cosf(fr), sn = sinf(fr);
    float o = v * c + ((lane < 32) ? sn : -sn) * partner;
    unsigned short* dst = (which ? kb : qb);
    dst[(size_t)s * DM + h * HD + lane] = f2b(o);
}

// ---- v blend + transpose via LDS tiles: vt[c][s] = blend(v,v1)[s][c] ----
__global__ void v_blend(const float* __restrict__ v, float* __restrict__ v1,
                        unsigned short* __restrict__ vt, const float* __restrict__ lambp,
                        int first) {
    __shared__ unsigned short tile[64 * 65];
    int t = threadIdx.x;
    int ts = blockIdx.x, tc = blockIdx.y;     // 64-row (s) x 64-col (c) tile
    float l = lambp[0];
#pragma unroll
    for (int j = 0; j < 16; ++j) {
        int idx = j * 256 + t;
        int s = idx >> 6, c = idx & 63;
        size_t gi = (size_t)(ts * 64 + s) * DM + tc * 64 + c;
        float val = v[gi];
        float v1v;
        if (first) { v1[gi] = val; v1v = val; } else v1v = v1[gi];
        tile[c * 65 + s] = f2b((1.f - l) * val + l * v1v);
    }
    __syncthreads();
#pragma unroll
    for (int j = 0; j < 16; ++j) {
        int idx = j * 256 + t;
        int c = idx >> 6, s = idx & 63;
        vt[(size_t)(tc * 64 + c) * SQ + ts * 64 + s] = tile[c * 65 + s];
    }
}

// ---- fused flash attention: one wave per (16-row q-tile, head) ----
// S = scale*Q K^T (MFMA, frags direct from L2), bit-mask, online softmax,
// P -> LDS (C-layout -> A-layout), O += P V (V^T frags direct from vt).
__global__ __launch_bounds__(64)
void flash_attn(const unsigned short* __restrict__ qb, const unsigned short* __restrict__ kb,
                const unsigned short* __restrict__ vt, const unsigned long long* __restrict__ mb,
                unsigned short* __restrict__ yb) {
    __shared__ unsigned short Ps[16 * 64];
    int lane = threadIdx.x;
    int qt = blockIdx.x & 63, h = blockIdx.x >> 6;
    int q0 = qt * 16;
    int r = lane & 15, q4 = lane >> 4;
    const unsigned short* qp = qb + (size_t)(q0 + r) * DM + h * HD + q4 * 8;
    short8 aq0 = *(const short8*)qp;
    short8 aq1 = *(const short8*)(qp + 32);
    floatx4 o[4] = {};
    float m[4] = {-1e30f, -1e30f, -1e30f, -1e30f};
    float l[4] = {0.f, 0.f, 0.f, 0.f};
    int nk = (qt >> 2) + 1;                    // causal: k-tiles 0 .. qt/4
    for (int kt = 0; kt < nk; ++kt) {
        int k0 = kt * 64;
        unsigned long long mw[4];
#pragma unroll
        for (int j = 0; j < 4; ++j) mw[j] = mb[(size_t)(q0 + q4 * 4 + j) * 16 + kt];
        unsigned long long any = mw[0] | mw[1] | mw[2] | mw[3];
        if (__ballot(any != 0ull) == 0ull) continue;   // whole tile masked (wave-uniform)
        short8 bk[4][2], bv[4][2];
#pragma unroll
        for (int ni = 0; ni < 4; ++ni) {
            const unsigned short* kp = kb + (size_t)(k0 + ni * 16 + r) * DM + h * HD + q4 * 8;
            bk[ni][0] = *(const short8*)kp;
            bk[ni][1] = *(const short8*)(kp + 32);
            const unsigned short* vp = vt + (size_t)(h * HD + ni * 16 + r) * SQ + k0 + q4 * 8;
            bv[ni][0] = *(const short8*)vp;
            bv[ni][1] = *(const short8*)(vp + 32);
        }
        float sm[4][4];
#pragma unroll
        for (int ni = 0; ni < 4; ++ni) {
            floatx4 z = {};
            z = __builtin_amdgcn_mfma_f32_16x16x32_bf16(aq0, bk[ni][0], z, 0, 0, 0);
            z = __builtin_amdgcn_mfma_f32_16x16x32_bf16(aq1, bk[ni][1], z, 0, 0, 0);
#pragma unroll
            for (int j = 0; j < 4; ++j) {
                float sv = z[j] * 0.125f;
                bool bit = (mw[j] >> (ni * 16 + r)) & 1ull;
                sm[ni][j] = bit ? sv : -__builtin_inff();
            }
        }
        float alpha[4];
#pragma unroll
        for (int j = 0; j < 4; ++j) {
            float v = fmaxf(fmaxf(sm[0][j], sm[1][j]), fmaxf(sm[2][j], sm[3][j]));
#pragma unroll
            for (int d = 1; d < 16; d <<= 1) v = fmaxf(v, __shfl_xor(v, d, 64));
            float mn = fmaxf(m[j], v);          // stays finite even if tile all-masked
            alpha[j] = __expf(m[j] - mn);
            m[j] = mn;
        }
        float p[4][4];
        float rs[4] = {0.f, 0.f, 0.f, 0.f};
#pragma unroll
        for (int ni = 0; ni < 4; ++ni)
#pragma unroll
            for (int j = 0; j < 4; ++j) {
                p[ni][j] = __expf(sm[ni][j] - m[j]);   // exp(-inf)=0 for masked
                rs[j] += p[ni][j];
            }
#pragma unroll
        for (int j = 0; j < 4; ++j) {
            float v = rs[j];
#pragma unroll
            for (int d = 1; d < 16; d <<= 1) v += __shfl_xor(v, d, 64);
            l[j] = l[j] * alpha[j] + v;
        }
#pragma unroll
        for (int ni = 0; ni < 4; ++ni)
#pragma unroll
            for (int j = 0; j < 4; ++j) {
                o[ni][j] *= alpha[j];
                Ps[(q4 * 4 + j) * 64 + ni * 16 + r] = f2b(p[ni][j]);
            }
        // single wave: no barrier needed; compiler inserts lgkmcnt waits
        short8 ap0 = *(const short8*)(Ps + r * 64 + q4 * 8);
        short8 ap1 = *(const short8*)(Ps + r * 64 + 32 + q4 * 8);
#pragma unroll
        for (int ni = 0; ni < 4; ++ni) {
            o[ni] = __builtin_amdgcn_mfma_f32_16x16x32_bf16(ap0, bv[ni][0], o[ni], 0, 0, 0);
            o[ni] = __builtin_amdgcn_mfma_f32_16x16x32_bf16(ap1, bv[ni][1], o[ni], 0, 0, 0);
        }
    }
#pragma unroll
    for (int j = 0; j < 4; ++j) l[j] = 1.f / l[j];
#pragma unroll
    for (int ni = 0; ni < 4; ++ni)
#pragma unroll
        for (int j = 0; j < 4; ++j)
            yb[(size_t)(q0 + q4 * 4 + j) * DM + h * HD + ni * 16 + r] = f2b(o[ni][j] * l[j]);
}

// ---- LDS-tiled MFMA GEMM (m97 structure): C[z] = act(scale*A[z]*B[z]^T + add) ----
template<int BM, int BN>
__global__ __launch_bounds__(256, 2)
void gemm_t(const unsigned short* __restrict__ A, int lda, long long sA,
            const unsigned short* __restrict__ B, int ldb, long long sB,
            float* Cf, unsigned short* Cb, int ldc, long long sC,
            const float* __restrict__ addsrc, int ldadd,
            int K, float scale, int act) {
    constexpr int BK = 32;
    constexpr int MI = BM / 32, NI = BN / 32;
    constexpr int CA = BM / 16, CB = BN / 16;
    constexpr int CAW = CA / 4, CBW = CB / 4;
    __shared__ unsigned short As[BM * BK];
    __shared__ unsigned short Bs[BN * BK];

    int t = threadIdx.x;
    int wave = t >> 6, lane = t & 63;
    int m0 = blockIdx.y * BM, n0 = blockIdx.x * BN;
    int z = blockIdx.z;
    const unsigned short* Ab = A + (size_t)z * sA;
    const unsigned short* Bb = B + (size_t)z * sB;

    int r = lane & 15, q4 = lane >> 4;
    int sr = lane >> 2, sseg = lane & 3;
    int wmo = (wave >> 1) * (BM / 2);
    int wno = (wave & 1) * (BN / 2);

    floatx4 acc[MI][NI] = {};

    for (int k0 = 0; k0 < K; k0 += BK) {
#pragma unroll
        for (int j = 0; j < CAW; ++j) {
            int c = wave * CAW + j;
            const unsigned short* g = Ab + (size_t)(m0 + c * 16 + sr) * lda + k0 + sseg * 8;
            __builtin_amdgcn_global_load_lds((GU32*)g, (LU32*)(As + c * 512), 16, 0, 0);
        }
#pragma unroll
        for (int j = 0; j < CBW; ++j) {
            int c = wave * CBW + j;
            const unsigned short* g = Bb + (size_t)(n0 + c * 16 + sr) * ldb + k0 + sseg * 8;
            __builtin_amdgcn_global_load_lds((GU32*)g, (LU32*)(Bs + c * 512), 16, 0, 0);
        }
        __syncthreads();

        short8 af[MI], bfr[NI];
#pragma unroll
        for (int mi = 0; mi < MI; ++mi)
            af[mi] = *(const short8*)(As + (wmo + mi * 16 + r) * BK + q4 * 8);
#pragma unroll
        for (int ni = 0; ni < NI; ++ni)
            bfr[ni] = *(const short8*)(Bs + (wno + ni * 16 + r) * BK + q4 * 8);
#pragma unroll
        for (int mi = 0; mi < MI; ++mi)
#pragma unroll
            for (int ni = 0; ni < NI; ++ni)
                acc[mi][ni] = __builtin_amdgcn_mfma_f32_16x16x32_bf16(af[mi], bfr[ni], acc[mi][ni], 0, 0, 0);
        __syncthreads();
    }

    size_t cz = (size_t)z * sC;
#pragma unroll
    for (int mi = 0; mi < MI; ++mi) {
#pragma unroll
        for (int ni = 0; ni < NI; ++ni) {
            int col = n0 + wno + ni * 16 + r;
#pragma unroll
            for (int j = 0; j < 4; ++j) {
                int row = m0 + wmo + mi * 16 + q4 * 4 + j;
                float v = acc[mi][ni][j] * scale;
                if (addsrc) v += addsrc[(size_t)row * ldadd + col];
                if (act == 1) { v = fmaxf(v, 0.f); v = v * v; }
                if (Cf) Cf[cz + (size_t)row * ldc + col] = v;
                if (Cb) Cb[cz + (size_t)row * ldc + col] = f2b(v);
            }
        }
    }
}

extern "C" void kernel_launch(void* const* d_in, const int* in_sizes, int n_in,
                              void* d_out, int out_size, void* d_ws, size_t ws_size,
                              hipStream_t stream) {
    const float* x_in    = (const float*)d_in[0];
    const float* Wq      = (const float*)d_in[1];
    const float* Wk      = (const float*)d_in[2];
    const float* Wv      = (const float*)d_in[3];
    const float* Wo      = (const float*)d_in[4];
    const float* lamb    = (const float*)d_in[5];
    const float* lambdas = (const float*)d_in[6];
    const float* Wfc     = (const float*)d_in[7];
    const float* Wp      = (const float*)d_in[8];
    const int*   levels  = (const int*)d_in[9];
    const int*   sidx    = (const int*)d_in[10];
    float* out = (float*)d_out;

    char* ws = (char*)d_ws;
    size_t off = 0;
    auto alloc = [&](size_t b) { void* p = ws + off; off = (off + b + 255) & ~(size_t)255; return p; };

    unsigned short* wq_b  = (unsigned short*)alloc((size_t)NL * DM * DM * 2);
    unsigned short* wk_b  = (unsigned short*)alloc((size_t)NL * DM * DM * 2);
    unsigned short* wv_b  = (unsigned short*)alloc((size_t)NL * DM * DM * 2);
    unsigned short* wo_b  = (unsigned short*)alloc((size_t)NL * DM * DM * 2);
    unsigned short* wfc_b = (unsigned short*)alloc((size_t)NL * DFF * DM * 2);
    unsigned short* wp_b  = (unsigned short*)alloc((size_t)NL * DM * DFF * 2);
    int* cpad             = (int*)alloc((SQ + 1) * 4);
    unsigned long long* mb = (unsigned long long*)alloc((size_t)SQ * 16 * 8);
    float* x    = (float*)alloc((size_t)SQ * DM * 4);
    float* x0   = (float*)alloc((size_t)SQ * DM * 4);
    float* xl   = (float*)alloc((size_t)SQ * DM * 4);
    float* qf   = (float*)alloc((size_t)SQ * DM * 4);
    float* kf   = (float*)alloc((size_t)SQ * DM * 4);
    float* vf   = (float*)alloc((size_t)SQ * DM * 4);
    float* v1   = (float*)alloc((size_t)SQ * DM * 4);
    unsigned short* xn_b = (unsigned short*)alloc((size_t)SQ * DM * 2);
    unsigned short* qb   = (unsigned short*)alloc((size_t)SQ * DM * 2);
    unsigned short* kb   = (unsigned short*)alloc((size_t)SQ * DM * 2);
    unsigned short* vt   = (unsigned short*)alloc((size_t)SQ * DM * 2);
    unsigned short* y_b  = (unsigned short*)alloc((size_t)SQ * DM * 2);
    unsigned short* xh_b = (unsigned short*)alloc((size_t)SQ * DM * 2);
    unsigned short* h_b  = (unsigned short*)alloc((size_t)SQ * DFF * 2);

    if (off > ws_size) return;

    const long long WSTRIDE = (long long)NL * DM * DM;
    const long long XSTRIDE = (long long)SQ * DM;

    convert_w<<<1024, 256, 0, stream>>>(Wq, wq_b, (long)NL * DM * DM / 4);
    convert_w<<<1024, 256, 0, stream>>>(Wk, wk_b, (long)NL * DM * DM / 4);
    convert_w<<<1024, 256, 0, stream>>>(Wv, wv_b, (long)NL * DM * DM / 4);
    convert_w<<<1024, 256, 0, stream>>>(Wo, wo_b, (long)NL * DM * DM / 4);
    convert_w<<<2048, 256, 0, stream>>>(Wfc, wfc_b, (long)NL * DFF * DM / 4);
    convert_w<<<2048, 256, 0, stream>>>(Wp, wp_b, (long)NL * DM * DFF / 4);

    scan_levels<<<1, 1024, 0, stream>>>(levels, cpad);
    build_mask_bits<<<4096, 256, 0, stream>>>(levels, sidx, cpad, mb);

    rms_kernel<<<SQ, 256, 0, stream>>>(x_in, x, x0, nullptr);

    for (int i = 0; i < NL; ++i) {
        xl_rms<<<SQ, 256, 0, stream>>>(x, x0, lambdas + 2 * i, xl, xn_b);

        // fused QKV (z selects Wq/Wk/Wv -> qf/kf/vf), 384 blocks
        gemm_t<128, 64><<<dim3(16, 8, 3), 256, 0, stream>>>(
            xn_b, DM, 0, wq_b + (size_t)i * DM * DM, DM, WSTRIDE,
            qf, nullptr, DM, XSTRIDE, nullptr, 0, DM, 1.f, 0);

        qk_norm_rope<<<8192, 256, 0, stream>>>(qf, kf, qb, kb);
        v_blend<<<dim3(16, 16), 256, 0, stream>>>(vf, v1, vt, lamb + i, (i == 0) ? 1 : 0);

        // fused attention -> y_b
        flash_attn<<<1024, 64, 0, stream>>>(qb, kb, vt, mb, y_b);

        // x = xl + y @ Wo^T
        gemm_t<64, 64><<<dim3(16, 16, 1), 256, 0, stream>>>(
            y_b, DM, 0, wo_b + (size_t)i * DM * DM, DM, 0,
            x, nullptr, DM, 0, xl, DM, DM, 1.f, 0);

        // FFN
        rms_kernel<<<SQ, 256, 0, stream>>>(x, nullptr, nullptr, xh_b);
        gemm_t<128, 64><<<dim3(64, 8, 1), 256, 0, stream>>>(
            xh_b, DM, 0, wfc_b + (size_t)i * DFF * DM, DM, 0,
            nullptr, h_b, DFF, 0, nullptr, 0, DM, 1.f, 1);
        gemm_t<64, 64><<<dim3(16, 16, 1), 256, 0, stream>>>(
            h_b, DFF, 0, wp_b + (size_t)i * DM * DFF, DFF, 0,
            x, nullptr, DM, 0, x, DM, DFF, 1.f, 0);
    }

    rms_kernel<<<SQ, 256, 0, stream>>>(x, out, nullptr, nullptr);
}

// Round 4
// 1209.291 us; speedup vs baseline: 2.6001x; 1.0533x over previous
//
#include <hip/hip_runtime.h>

#define SQ 1024
#define DM 1024
#define NH 16
#define HD 64
#define NL 6
#define DFF 4096
#define EPS 1.1920929e-07f

typedef __attribute__((ext_vector_type(8))) short short8;
typedef __attribute__((ext_vector_type(4))) float floatx4;
typedef __attribute__((address_space(1))) const unsigned int GU32;
typedef __attribute__((address_space(3))) unsigned int LU32;

__device__ __forceinline__ unsigned short f2b(float f) {
    union { float f; unsigned int u; } x; x.f = f;
    unsigned int r = x.u + 0x7fffu + ((x.u >> 16) & 1u);
    return (unsigned short)(r >> 16);
}

__device__ __forceinline__ float wsum(float v) {
#pragma unroll
    for (int m = 32; m >= 1; m >>= 1) v += __shfl_xor(v, m, 64);
    return v;
}
__device__ __forceinline__ float bsum(float v) {
    __shared__ float sh[4];
    v = wsum(v);
    __syncthreads();
    if ((threadIdx.x & 63) == 0) sh[threadIdx.x >> 6] = v;
    __syncthreads();
    return sh[0] + sh[1] + sh[2] + sh[3];
}

// ---- fused f32 -> bf16 conversion for all 6 weight tensors (one launch) ----
__global__ void convert_all(const float* __restrict__ s0, const float* __restrict__ s1,
                            const float* __restrict__ s2, const float* __restrict__ s3,
                            const float* __restrict__ s4, const float* __restrict__ s5,
                            unsigned short* __restrict__ d0, unsigned short* __restrict__ d1,
                            unsigned short* __restrict__ d2, unsigned short* __restrict__ d3,
                            unsigned short* __restrict__ d4, unsigned short* __restrict__ d5) {
    const long ns = (long)NL * DM * DM / 4;        // 1572864 float4s per small tensor
    const long nb = (long)NL * DFF * DM / 4;       // 6291456 per big tensor
    const long total = 4 * ns + 2 * nb;
    long i = (long)blockIdx.x * 256 + threadIdx.x;
    long stride = (long)gridDim.x * 256;
    for (; i < total; i += stride) {
        const float* src; unsigned short* dst; long off;
        if (i < 4 * ns) {
            long seg = i / ns; off = i - seg * ns;
            src = (seg == 0) ? s0 : (seg == 1) ? s1 : (seg == 2) ? s2 : s3;
            dst = (seg == 0) ? d0 : (seg == 1) ? d1 : (seg == 2) ? d2 : d3;
        } else {
            long j = i - 4 * ns;
            if (j < nb) { src = s4; dst = d4; off = j; }
            else        { src = s5; dst = d5; off = j - nb; }
        }
        float4 v = ((const float4*)src)[off];
        ushort4 o;
        o.x = f2b(v.x); o.y = f2b(v.y); o.z = f2b(v.z); o.w = f2b(v.w);
        ((ushort4*)dst)[off] = o;
    }
}

// ---- markov mask prep ----
__global__ void scan_levels(const int* __restrict__ levels, int* __restrict__ cpad) {
    __shared__ int sh[SQ];
    int t = threadIdx.x;
    sh[t] = (levels[t] == 0) ? 1 : 0;
    __syncthreads();
    for (int off = 1; off < SQ; off <<= 1) {
        int v = (t >= off) ? sh[t - off] : 0;
        __syncthreads();
        sh[t] += v;
        __syncthreads();
    }
    cpad[t + 1] = sh[t];
    if (t == 0) cpad[0] = 0;
}

__global__ void build_mask_bits(const int* __restrict__ levels, const int* __restrict__ sidx,
                                const int* __restrict__ cpad, unsigned long long* __restrict__ mb) {
    int i = blockIdx.x * 256 + threadIdx.x;
    int q = i >> 10, k = i & 1023;
    bool causal = q >= k;
    bool same = sidx[q] == sidx[k];
    int cnt = cpad[q] - cpad[k + 1];
    bool markov = (levels[k] == 0) && (cnt > 0);
    bool pred = causal && same && !markov;
    unsigned long long bal = __ballot(pred);
    if ((threadIdx.x & 63) == 0) mb[(size_t)q * 16 + (k >> 6)] = bal;
}

// ---- row-wise rms ----
__global__ void rms_kernel(const float* __restrict__ in, float* o1, float* o2, unsigned short* ob) {
    int row = blockIdx.x, t = threadIdx.x;
    const float* rp = in + (size_t)row * DM;
    float v[4]; float ss = 0.f;
#pragma unroll
    for (int j = 0; j < 4; ++j) { v[j] = rp[t + j * 256]; ss += v[j] * v[j]; }
    ss = bsum(ss);
    float inv = rsqrtf(ss / (float)DM + EPS);
#pragma unroll
    for (int j = 0; j < 4; ++j) {
        float o = v[j] * inv;
        int c = t + j * 256;
        if (o1) o1[(size_t)row * DM + c] = o;
        if (o2) o2[(size_t)row * DM + c] = o;
        if (ob) ob[(size_t)row * DM + c] = f2b(o);
    }
}

// ---- xl = l0*x + l1*x0 (f32), xn = rms(xl) (bf16) ----
__global__ void xl_rms(const float* __restrict__ x, const float* __restrict__ x0,
                       const float* __restrict__ lam2, float* __restrict__ xl,
                       unsigned short* __restrict__ xnb) {
    int row = blockIdx.x, t = threadIdx.x;
    float l0 = lam2[0], l1 = lam2[1];
    const float* xp = x + (size_t)row * DM;
    const float* x0p = x0 + (size_t)row * DM;
    float v[4]; float ss = 0.f;
#pragma unroll
    for (int j = 0; j < 4; ++j) {
        int c = t + j * 256;
        v[j] = l0 * xp[c] + l1 * x0p[c];
        ss += v[j] * v[j];
    }
    ss = bsum(ss);
    float inv = rsqrtf(ss / (float)DM + EPS);
#pragma unroll
    for (int j = 0; j < 4; ++j) {
        int c = t + j * 256;
        xl[(size_t)row * DM + c] = v[j];
        xnb[(size_t)row * DM + c] = f2b(v[j] * inv);
    }
}

// ---- fused post-QKV: blocks [0,8192) = qk rms+rope; [8192,8448) = v blend+transpose ----
__global__ void qkv_post(const float* __restrict__ qf, const float* __restrict__ kf,
                         unsigned short* __restrict__ qb, unsigned short* __restrict__ kb,
                         const float* __restrict__ vf, float* __restrict__ v1,
                         unsigned short* __restrict__ vt, const float* __restrict__ lambp,
                         int first) {
    __shared__ unsigned short tile[64 * 65];
    int b = blockIdx.x;
    int t = threadIdx.x;
    if (b < 8192) {
        int wid = b * 4 + (t >> 6);
        int lane = t & 63;
        int which = wid >> 14;
        int idx = wid & 16383;
        int s = idx >> 4;
        int h = idx & 15;
        const float* src = (which ? kf : qf) + (size_t)s * DM + h * HD;
        float v = src[lane];
        float ss = v * v;
#pragma unroll
        for (int m = 32; m >= 1; m >>= 1) ss += __shfl_xor(ss, m, 64);
        v *= rsqrtf(ss / (float)HD + EPS);
        float partner = __shfl_xor(v, 32, 64);
        int j = lane & 31;
        float invf = expf(-((float)(2 * j) / (float)HD) * 9.210340371976184f);
        float fr = (float)s * invf;
        float c = cosf(fr), sn = sinf(fr);
        float o = v * c + ((lane < 32) ? sn : -sn) * partner;
        unsigned short* dst = (which ? kb : qb);
        dst[(size_t)s * DM + h * HD + lane] = f2b(o);
    } else {
        int bb = b - 8192;
        int ts = bb >> 4, tc = bb & 15;
        float l = lambp[0];
#pragma unroll
        for (int j = 0; j < 16; ++j) {
            int idx = j * 256 + t;
            int s = idx >> 6, c = idx & 63;
            size_t gi = (size_t)(ts * 64 + s) * DM + tc * 64 + c;
            float val = vf[gi];
            float v1v;
            if (first) { v1[gi] = val; v1v = val; } else v1v = v1[gi];
            tile[c * 65 + s] = f2b((1.f - l) * val + l * v1v);
        }
        __syncthreads();
#pragma unroll
        for (int j = 0; j < 16; ++j) {
            int idx = j * 256 + t;
            int c = idx >> 6, s = idx & 63;
            vt[(size_t)(tc * 64 + c) * SQ + ts * 64 + s] = tile[c * 65 + s];
        }
    }
}

// ---- split-K reduce with residual: x += p0+p1+p2+p3 (float4) ----
__global__ void reduce_add(float* __restrict__ x, const float* __restrict__ p) {
    int i = blockIdx.x * 256 + threadIdx.x;       // over SQ*DM/4
    const long n = (long)SQ * DM / 4;
    float4 a = ((const float4*)x)[i];
    float4 p0 = ((const float4*)p)[i];
    float4 p1 = ((const float4*)p)[i + n];
    float4 p2 = ((const float4*)p)[i + 2 * n];
    float4 p3 = ((const float4*)p)[i + 3 * n];
    a.x += p0.x + p1.x + p2.x + p3.x;
    a.y += p0.y + p1.y + p2.y + p3.y;
    a.z += p0.z + p1.z + p2.z + p3.z;
    a.w += p0.w + p1.w + p2.w + p3.w;
    ((float4*)x)[i] = a;
}

// ---- fused flash attention: one wave per (16-row q-tile, head) ----
__global__ __launch_bounds__(64)
void flash_attn(const unsigned short* __restrict__ qb, const unsigned short* __restrict__ kb,
                const unsigned short* __restrict__ vt, const unsigned long long* __restrict__ mb,
                unsigned short* __restrict__ yb) {
    __shared__ unsigned short Ps[16 * 64];
    int lane = threadIdx.x;
    int qt = blockIdx.x & 63, h = blockIdx.x >> 6;
    int q0 = qt * 16;
    int r = lane & 15, q4 = lane >> 4;
    const unsigned short* qp = qb + (size_t)(q0 + r) * DM + h * HD + q4 * 8;
    short8 aq0 = *(const short8*)qp;
    short8 aq1 = *(const short8*)(qp + 32);
    floatx4 o[4] = {};
    float m[4] = {-1e30f, -1e30f, -1e30f, -1e30f};
    float l[4] = {0.f, 0.f, 0.f, 0.f};
    int nk = (qt >> 2) + 1;
    for (int kt = 0; kt < nk; ++kt) {
        int k0 = kt * 64;
        unsigned long long mw[4];
#pragma unroll
        for (int j = 0; j < 4; ++j) mw[j] = mb[(size_t)(q0 + q4 * 4 + j) * 16 + kt];
        unsigned long long any = mw[0] | mw[1] | mw[2] | mw[3];
        if (__ballot(any != 0ull) == 0ull) continue;
        short8 bk[4][2], bv[4][2];
#pragma unroll
        for (int ni = 0; ni < 4; ++ni) {
            const unsigned short* kp = kb + (size_t)(k0 + ni * 16 + r) * DM + h * HD + q4 * 8;
            bk[ni][0] = *(const short8*)kp;
            bk[ni][1] = *(const short8*)(kp + 32);
            const unsigned short* vp = vt + (size_t)(h * HD + ni * 16 + r) * SQ + k0 + q4 * 8;
            bv[ni][0] = *(const short8*)vp;
            bv[ni][1] = *(const short8*)(vp + 32);
        }
        float sm[4][4];
#pragma unroll
        for (int ni = 0; ni < 4; ++ni) {
            floatx4 z = {};
            z = __builtin_amdgcn_mfma_f32_16x16x32_bf16(aq0, bk[ni][0], z, 0, 0, 0);
            z = __builtin_amdgcn_mfma_f32_16x16x32_bf16(aq1, bk[ni][1], z, 0, 0, 0);
#pragma unroll
            for (int j = 0; j < 4; ++j) {
                float sv = z[j] * 0.125f;
                bool bit = (mw[j] >> (ni * 16 + r)) & 1ull;
                sm[ni][j] = bit ? sv : -__builtin_inff();
            }
        }
        float alpha[4];
#pragma unroll
        for (int j = 0; j < 4; ++j) {
            float v = fmaxf(fmaxf(sm[0][j], sm[1][j]), fmaxf(sm[2][j], sm[3][j]));
#pragma unroll
            for (int d = 1; d < 16; d <<= 1) v = fmaxf(v, __shfl_xor(v, d, 64));
            float mn = fmaxf(m[j], v);
            alpha[j] = __expf(m[j] - mn);
            m[j] = mn;
        }
        float p[4][4];
        float rs[4] = {0.f, 0.f, 0.f, 0.f};
#pragma unroll
        for (int ni = 0; ni < 4; ++ni)
#pragma unroll
            for (int j = 0; j < 4; ++j) {
                p[ni][j] = __expf(sm[ni][j] - m[j]);
                rs[j] += p[ni][j];
            }
#pragma unroll
        for (int j = 0; j < 4; ++j) {
            float v = rs[j];
#pragma unroll
            for (int d = 1; d < 16; d <<= 1) v += __shfl_xor(v, d, 64);
            l[j] = l[j] * alpha[j] + v;
        }
#pragma unroll
        for (int ni = 0; ni < 4; ++ni)
#pragma unroll
            for (int j = 0; j < 4; ++j) {
                o[ni][j] *= alpha[j];
                Ps[(q4 * 4 + j) * 64 + ni * 16 + r] = f2b(p[ni][j]);
            }
        short8 ap0 = *(const short8*)(Ps + r * 64 + q4 * 8);
        short8 ap1 = *(const short8*)(Ps + r * 64 + 32 + q4 * 8);
#pragma unroll
        for (int ni = 0; ni < 4; ++ni) {
            o[ni] = __builtin_amdgcn_mfma_f32_16x16x32_bf16(ap0, bv[ni][0], o[ni], 0, 0, 0);
            o[ni] = __builtin_amdgcn_mfma_f32_16x16x32_bf16(ap1, bv[ni][1], o[ni], 0, 0, 0);
        }
    }
#pragma unroll
    for (int j = 0; j < 4; ++j) l[j] = 1.f / l[j];
#pragma unroll
    for (int ni = 0; ni < 4; ++ni)
#pragma unroll
        for (int j = 0; j < 4; ++j)
            yb[(size_t)(q0 + q4 * 4 + j) * DM + h * HD + ni * 16 + r] = f2b(o[ni][j] * l[j]);
}

// ---- LDS-tiled MFMA GEMM (m97 structure): C[z] = act(scale*A[z]*B[z]^T + add) ----
// z-strides are in ELEMENTS and can implement batches (stride M*K) or split-K (stride Ksub).
template<int BM, int BN>
__global__ __launch_bounds__(256, 2)
void gemm_t(const unsigned short* __restrict__ A, int lda, long long sA,
            const unsigned short* __restrict__ B, int ldb, long long sB,
            float* Cf, unsigned short* Cb, int ldc, long long sC,
            const float* __restrict__ addsrc, int ldadd,
            int K, float scale, int act) {
    constexpr int BK = 32;
    constexpr int MI = BM / 32, NI = BN / 32;
    constexpr int CA = BM / 16, CB = BN / 16;
    constexpr int CAW = CA / 4, CBW = CB / 4;
    __shared__ unsigned short As[BM * BK];
    __shared__ unsigned short Bs[BN * BK];

    int t = threadIdx.x;
    int wave = t >> 6, lane = t & 63;
    int m0 = blockIdx.y * BM, n0 = blockIdx.x * BN;
    int z = blockIdx.z;
    const unsigned short* Ab = A + (size_t)z * sA;
    const unsigned short* Bb = B + (size_t)z * sB;

    int r = lane & 15, q4 = lane >> 4;
    int sr = lane >> 2, sseg = lane & 3;
    int wmo = (wave >> 1) * (BM / 2);
    int wno = (wave & 1) * (BN / 2);

    floatx4 acc[MI][NI] = {};

    for (int k0 = 0; k0 < K; k0 += BK) {
#pragma unroll
        for (int j = 0; j < CAW; ++j) {
            int c = wave * CAW + j;
            const unsigned short* g = Ab + (size_t)(m0 + c * 16 + sr) * lda + k0 + sseg * 8;
            __builtin_amdgcn_global_load_lds((GU32*)g, (LU32*)(As + c * 512), 16, 0, 0);
        }
#pragma unroll
        for (int j = 0; j < CBW; ++j) {
            int c = wave * CBW + j;
            const unsigned short* g = Bb + (size_t)(n0 + c * 16 + sr) * ldb + k0 + sseg * 8;
            __builtin_amdgcn_global_load_lds((GU32*)g, (LU32*)(Bs + c * 512), 16, 0, 0);
        }
        __syncthreads();

        short8 af[MI], bfr[NI];
#pragma unroll
        for (int mi = 0; mi < MI; ++mi)
            af[mi] = *(const short8*)(As + (wmo + mi * 16 + r) * BK + q4 * 8);
#pragma unroll
        for (int ni = 0; ni < NI; ++ni)
            bfr[ni] = *(const short8*)(Bs + (wno + ni * 16 + r) * BK + q4 * 8);
#pragma unroll
        for (int mi = 0; mi < MI; ++mi)
#pragma unroll
            for (int ni = 0; ni < NI; ++ni)
                acc[mi][ni] = __builtin_amdgcn_mfma_f32_16x16x32_bf16(af[mi], bfr[ni], acc[mi][ni], 0, 0, 0);
        __syncthreads();
    }

    size_t cz = (size_t)z * sC;
#pragma unroll
    for (int mi = 0; mi < MI; ++mi) {
#pragma unroll
        for (int ni = 0; ni < NI; ++ni) {
            int col = n0 + wno + ni * 16 + r;
#pragma unroll
            for (int j = 0; j < 4; ++j) {
                int row = m0 + wmo + mi * 16 + q4 * 4 + j;
                float v = acc[mi][ni][j] * scale;
                if (addsrc) v += addsrc[(size_t)row * ldadd + col];
                if (act == 1) { v = fmaxf(v, 0.f); v = v * v; }
                if (Cf) Cf[cz + (size_t)row * ldc + col] = v;
                if (Cb) Cb[cz + (size_t)row * ldc + col] = f2b(v);
            }
        }
    }
}

extern "C" void kernel_launch(void* const* d_in, const int* in_sizes, int n_in,
                              void* d_out, int out_size, void* d_ws, size_t ws_size,
                              hipStream_t stream) {
    const float* x_in    = (const float*)d_in[0];
    const float* Wq      = (const float*)d_in[1];
    const float* Wk      = (const float*)d_in[2];
    const float* Wv      = (const float*)d_in[3];
    const float* Wo      = (const float*)d_in[4];
    const float* lamb    = (const float*)d_in[5];
    const float* lambdas = (const float*)d_in[6];
    const float* Wfc     = (const float*)d_in[7];
    const float* Wp      = (const float*)d_in[8];
    const int*   levels  = (const int*)d_in[9];
    const int*   sidx    = (const int*)d_in[10];
    float* out = (float*)d_out;

    char* ws = (char*)d_ws;
    size_t off = 0;
    auto alloc = [&](size_t b) { void* p = ws + off; off = (off + b + 255) & ~(size_t)255; return p; };

    unsigned short* wq_b  = (unsigned short*)alloc((size_t)NL * DM * DM * 2);
    unsigned short* wk_b  = (unsigned short*)alloc((size_t)NL * DM * DM * 2);
    unsigned short* wv_b  = (unsigned short*)alloc((size_t)NL * DM * DM * 2);
    unsigned short* wo_b  = (unsigned short*)alloc((size_t)NL * DM * DM * 2);
    unsigned short* wfc_b = (unsigned short*)alloc((size_t)NL * DFF * DM * 2);
    unsigned short* wp_b  = (unsigned short*)alloc((size_t)NL * DM * DFF * 2);
    int* cpad             = (int*)alloc((SQ + 1) * 4);
    unsigned long long* mb = (unsigned long long*)alloc((size_t)SQ * 16 * 8);
    float* x    = (float*)alloc((size_t)SQ * DM * 4);
    float* x0   = (float*)alloc((size_t)SQ * DM * 4);
    float* xl   = (float*)alloc((size_t)SQ * DM * 4);
    float* qf   = (float*)alloc((size_t)SQ * DM * 4);
    float* kf   = (float*)alloc((size_t)SQ * DM * 4);
    float* vf   = (float*)alloc((size_t)SQ * DM * 4);
    float* v1   = (float*)alloc((size_t)SQ * DM * 4);
    float* pp   = (float*)alloc((size_t)4 * SQ * DM * 4);   // split-K partials
    unsigned short* xn_b = (unsigned short*)alloc((size_t)SQ * DM * 2);
    unsigned short* qb   = (unsigned short*)alloc((size_t)SQ * DM * 2);
    unsigned short* kb   = (unsigned short*)alloc((size_t)SQ * DM * 2);
    unsigned short* vt   = (unsigned short*)alloc((size_t)SQ * DM * 2);
    unsigned short* y_b  = (unsigned short*)alloc((size_t)SQ * DM * 2);
    unsigned short* xh_b = (unsigned short*)alloc((size_t)SQ * DM * 2);
    unsigned short* h_b  = (unsigned short*)alloc((size_t)SQ * DFF * 2);

    if (off > ws_size) return;

    const long long WSTRIDE = (long long)NL * DM * DM;
    const long long XSTRIDE = (long long)SQ * DM;

    convert_all<<<2048, 256, 0, stream>>>(Wq, Wk, Wv, Wo, Wfc, Wp,
                                          wq_b, wk_b, wv_b, wo_b, wfc_b, wp_b);

    scan_levels<<<1, 1024, 0, stream>>>(levels, cpad);
    build_mask_bits<<<4096, 256, 0, stream>>>(levels, sidx, cpad, mb);

    rms_kernel<<<SQ, 256, 0, stream>>>(x_in, x, x0, nullptr);

    for (int i = 0; i < NL; ++i) {
        xl_rms<<<SQ, 256, 0, stream>>>(x, x0, lambdas + 2 * i, xl, xn_b);

        // fused QKV, 128x128 tiles, z selects Wq/Wk/Wv -> qf/kf/vf (192 blocks)
        gemm_t<128, 128><<<dim3(8, 8, 3), 256, 0, stream>>>(
            xn_b, DM, 0, wq_b + (size_t)i * DM * DM, DM, WSTRIDE,
            qf, nullptr, DM, XSTRIDE, nullptr, 0, DM, 1.f, 0);

        // fused qk rms+rope (blocks 0..8191) + v blend/transpose (blocks 8192..8447)
        qkv_post<<<8448, 256, 0, stream>>>(qf, kf, qb, kb, vf, v1, vt, lamb + i, (i == 0) ? 1 : 0);

        flash_attn<<<1024, 64, 0, stream>>>(qb, kb, vt, mb, y_b);

        // x = xl + y @ Wo^T  (64x64 tiles, 256 blocks)
        gemm_t<64, 64><<<dim3(16, 16, 1), 256, 0, stream>>>(
            y_b, DM, 0, wo_b + (size_t)i * DM * DM, DM, 0,
            x, nullptr, DM, 0, xl, DM, DM, 1.f, 0);

        // FFN
        rms_kernel<<<SQ, 256, 0, stream>>>(x, nullptr, nullptr, xh_b);
        gemm_t<128, 128><<<dim3(32, 8, 1), 256, 0, stream>>>(
            xh_b, DM, 0, wfc_b + (size_t)i * DFF * DM, DM, 0,
            nullptr, h_b, DFF, 0, nullptr, 0, DM, 1.f, 1);
        // proj: split-K=4 (z strides Ksub=1024 along K), 128x128 tiles, 256 blocks
        gemm_t<128, 128><<<dim3(8, 8, 4), 256, 0, stream>>>(
            h_b, DFF, 1024, wp_b + (size_t)i * DM * DFF, DFF, 1024,
            pp, nullptr, DM, (long long)SQ * DM, nullptr, 0, 1024, 1.f, 0);
        reduce_add<<<SQ * DM / 4 / 256, 256, 0, stream>>>(x, pp);
    }

    rms_kernel<<<SQ, 256, 0, stream>>>(x, out, nullptr, nullptr);
}